// Round 1
// baseline (583.548 us; speedup 1.0000x reference)
//
#include <hip/hip_runtime.h>

#define R_BINS 50
#define NFEAT 7
#define HSZ (R_BINS * NFEAT)   // 350 floats
#define NWAVE 4                 // 256 threads / 64

__global__ __launch_bounds__(256) void disk_hist_kernel(
    const float* __restrict__ pos,
    const float* __restrict__ vel,
    const float* __restrict__ mass,
    float* __restrict__ ghist,
    int n)
{
    __shared__ float sh[NWAVE][HSZ];

    // zero block-private histograms
    for (int i = threadIdx.x; i < NWAVE * HSZ; i += blockDim.x)
        ((float*)sh)[i] = 0.0f;
    __syncthreads();

    float* h = sh[threadIdx.x >> 6];

    const int tid    = blockIdx.x * blockDim.x + threadIdx.x;
    const int stride = gridDim.x * blockDim.x;
    const int nquads = n >> 2;

    const float4* pos4  = (const float4*)pos;
    const float4* vel4  = (const float4*)vel;
    const float4* mass4 = (const float4*)mass;

    for (int q = tid; q < nquads; q += stride) {
        float4 p0 = pos4[3*q + 0];
        float4 p1 = pos4[3*q + 1];
        float4 p2 = pos4[3*q + 2];
        float4 v0 = vel4[3*q + 0];
        float4 v1 = vel4[3*q + 1];
        float4 v2 = vel4[3*q + 2];
        float4 m  = mass4[q];

        float px[4] = {p0.x, p0.w, p1.z, p2.y};
        float py[4] = {p0.y, p1.x, p1.w, p2.z};
        float vx[4] = {v0.x, v0.w, v1.z, v2.y};
        float vy[4] = {v0.y, v1.x, v1.w, v2.z};
        float vz[4] = {v0.z, v1.y, v2.x, v2.w};
        float mm[4] = {m.x,  m.y,  m.z,  m.w};

        #pragma unroll
        for (int k = 0; k < 4; ++k) {
            float x = px[k], y = py[k];
            float r = sqrtf(x * x + y * y);
            int bin = (int)floorf(r * 5.0f);   // DR = 0.2
            if (bin < 0 || bin >= R_BINS) continue;
            float invr = 1.0f / r;
            float vr = (x * vx[k] + y * vy[k]) * invr;
            float vp = (y * vx[k] - x * vy[k]) * invr;
            float w  = mm[k];
            float* b = h + bin * NFEAT;
            atomicAdd(b + 0, w);
            atomicAdd(b + 1, w * vr);
            atomicAdd(b + 2, w * vr * vr);
            atomicAdd(b + 3, w * vp);
            atomicAdd(b + 4, w * vp * vp);
            atomicAdd(b + 5, w * vz[k]);
            atomicAdd(b + 6, w * vz[k] * vz[k]);
        }
    }

    // scalar tail (N=16M is divisible by 4, but be safe)
    for (int p = (nquads << 2) + tid; p < n; p += stride) {
        float x = pos[3*p], y = pos[3*p + 1];
        float r = sqrtf(x * x + y * y);
        int bin = (int)floorf(r * 5.0f);
        if (bin < 0 || bin >= R_BINS) continue;
        float invr = 1.0f / r;
        float vxs = vel[3*p], vys = vel[3*p + 1], vzs = vel[3*p + 2];
        float vr = (x * vxs + y * vys) * invr;
        float vp = (y * vxs - x * vys) * invr;
        float w  = mass[p];
        float* b = h + bin * NFEAT;
        atomicAdd(b + 0, w);
        atomicAdd(b + 1, w * vr);
        atomicAdd(b + 2, w * vr * vr);
        atomicAdd(b + 3, w * vp);
        atomicAdd(b + 4, w * vp * vp);
        atomicAdd(b + 5, w * vzs);
        atomicAdd(b + 6, w * vzs * vzs);
    }

    __syncthreads();

    // merge wave copies, one global atomic per histogram cell per block
    for (int i = threadIdx.x; i < HSZ; i += blockDim.x) {
        float s = sh[0][i] + sh[1][i] + sh[2][i] + sh[3][i];
        atomicAdd(ghist + i, s);
    }
}

__global__ void disk_finalize_kernel(const float* __restrict__ gh,
                                     float* __restrict__ out)
{
    int b = threadIdx.x;
    if (b >= R_BINS) return;
    const float* s = gh + b * NFEAT;
    float inv  = 1.0f / s[0];
    float vr_m = s[1] * inv, vr2 = s[2] * inv;
    float vp_m = s[3] * inv, vp2 = s[4] * inv;
    float vz_m = s[5] * inv, vz2 = s[6] * inv;
    out[0 * R_BINS + b] = vp_m;
    out[1 * R_BINS + b] = sqrtf(vp2 - vp_m * vp_m);
    out[2 * R_BINS + b] = vr_m;
    out[3 * R_BINS + b] = sqrtf(vr2 - vr_m * vr_m);
    out[4 * R_BINS + b] = vz_m;
    out[5 * R_BINS + b] = sqrtf(vz2 - vz_m * vz_m);
}

extern "C" void kernel_launch(void* const* d_in, const int* in_sizes, int n_in,
                              void* d_out, int out_size, void* d_ws, size_t ws_size,
                              hipStream_t stream)
{
    const float* pos  = (const float*)d_in[0];
    const float* vel  = (const float*)d_in[1];
    const float* mass = (const float*)d_in[2];
    float* out   = (float*)d_out;
    float* ghist = (float*)d_ws;
    int n = in_sizes[2];   // masses: one per particle

    hipMemsetAsync(ghist, 0, HSZ * sizeof(float), stream);

    disk_hist_kernel<<<2048, 256, 0, stream>>>(pos, vel, mass, ghist, n);
    disk_finalize_kernel<<<1, 64, 0, stream>>>(ghist, out);
}

// Round 2
// 579.953 us; speedup vs baseline: 1.0062x; 1.0062x over previous
//
#include <hip/hip_runtime.h>

#define R_BINS 50
#define NFEAT 7
#define HSZ (R_BINS * NFEAT)   // 350 floats
#define NCOPY 32                // lane-indexed sub-copies: >=2 lanes/copy per wave instr

__global__ __launch_bounds__(256) void disk_hist_kernel(
    const float* __restrict__ pos,
    const float* __restrict__ vel,
    const float* __restrict__ mass,
    float* __restrict__ ghist,
    int n)
{
    __shared__ float sh[NCOPY * HSZ];   // 44.8 KB -> 3 blocks/CU

    for (int i = threadIdx.x; i < NCOPY * HSZ; i += blockDim.x)
        sh[i] = 0.0f;
    __syncthreads();

    float* h = sh + (threadIdx.x & (NCOPY - 1)) * HSZ;

    const int tid    = blockIdx.x * blockDim.x + threadIdx.x;
    const int stride = gridDim.x * blockDim.x;
    const int nquads = n >> 2;

    const float4* pos4  = (const float4*)pos;
    const float4* vel4  = (const float4*)vel;
    const float4* mass4 = (const float4*)mass;

    for (int q = tid; q < nquads; q += stride) {
        float4 p0 = pos4[3*q + 0];
        float4 p1 = pos4[3*q + 1];
        float4 p2 = pos4[3*q + 2];
        float4 v0 = vel4[3*q + 0];
        float4 v1 = vel4[3*q + 1];
        float4 v2 = vel4[3*q + 2];
        float4 m  = mass4[q];

        float px[4] = {p0.x, p0.w, p1.z, p2.y};
        float py[4] = {p0.y, p1.x, p1.w, p2.z};
        float vx[4] = {v0.x, v0.w, v1.z, v2.y};
        float vy[4] = {v0.y, v1.x, v1.w, v2.z};
        float vz[4] = {v0.z, v1.y, v2.x, v2.w};
        float mm[4] = {m.x,  m.y,  m.z,  m.w};

        #pragma unroll
        for (int k = 0; k < 4; ++k) {
            float x = px[k], y = py[k];
            float r = sqrtf(x * x + y * y);
            int bin = (int)floorf(r * 5.0f);   // DR = 0.2
            if (bin < 0 || bin >= R_BINS) continue;
            float invr = 1.0f / r;
            float vr = (x * vx[k] + y * vy[k]) * invr;
            float vp = (y * vx[k] - x * vy[k]) * invr;
            float w  = mm[k];
            float* b = h + bin * NFEAT;
            atomicAdd(b + 0, w);
            atomicAdd(b + 1, w * vr);
            atomicAdd(b + 2, w * vr * vr);
            atomicAdd(b + 3, w * vp);
            atomicAdd(b + 4, w * vp * vp);
            atomicAdd(b + 5, w * vz[k]);
            atomicAdd(b + 6, w * vz[k] * vz[k]);
        }
    }

    // scalar tail
    for (int p = (nquads << 2) + tid; p < n; p += stride) {
        float x = pos[3*p], y = pos[3*p + 1];
        float r = sqrtf(x * x + y * y);
        int bin = (int)floorf(r * 5.0f);
        if (bin < 0 || bin >= R_BINS) continue;
        float invr = 1.0f / r;
        float vxs = vel[3*p], vys = vel[3*p + 1], vzs = vel[3*p + 2];
        float vr = (x * vxs + y * vys) * invr;
        float vp = (y * vxs - x * vys) * invr;
        float w  = mass[p];
        float* b = h + bin * NFEAT;
        atomicAdd(b + 0, w);
        atomicAdd(b + 1, w * vr);
        atomicAdd(b + 2, w * vr * vr);
        atomicAdd(b + 3, w * vp);
        atomicAdd(b + 4, w * vp * vp);
        atomicAdd(b + 5, w * vzs);
        atomicAdd(b + 6, w * vzs * vzs);
    }

    __syncthreads();

    // merge the 32 copies; one global atomic per cell per block
    for (int i = threadIdx.x; i < HSZ; i += blockDim.x) {
        float s = 0.0f;
        #pragma unroll
        for (int c = 0; c < NCOPY; ++c)
            s += sh[c * HSZ + i];
        atomicAdd(ghist + i, s);
    }
}

__global__ void disk_finalize_kernel(const float* __restrict__ gh,
                                     float* __restrict__ out)
{
    int b = threadIdx.x;
    if (b >= R_BINS) return;
    const float* s = gh + b * NFEAT;
    float inv  = 1.0f / s[0];
    float vr_m = s[1] * inv, vr2 = s[2] * inv;
    float vp_m = s[3] * inv, vp2 = s[4] * inv;
    float vz_m = s[5] * inv, vz2 = s[6] * inv;
    out[0 * R_BINS + b] = vp_m;
    out[1 * R_BINS + b] = sqrtf(vp2 - vp_m * vp_m);
    out[2 * R_BINS + b] = vr_m;
    out[3 * R_BINS + b] = sqrtf(vr2 - vr_m * vr_m);
    out[4 * R_BINS + b] = vz_m;
    out[5 * R_BINS + b] = sqrtf(vz2 - vz_m * vz_m);
}

extern "C" void kernel_launch(void* const* d_in, const int* in_sizes, int n_in,
                              void* d_out, int out_size, void* d_ws, size_t ws_size,
                              hipStream_t stream)
{
    const float* pos  = (const float*)d_in[0];
    const float* vel  = (const float*)d_in[1];
    const float* mass = (const float*)d_in[2];
    float* out   = (float*)d_out;
    float* ghist = (float*)d_ws;
    int n = in_sizes[2];   // masses: one per particle

    hipMemsetAsync(ghist, 0, HSZ * sizeof(float), stream);

    // 3 blocks/CU (LDS-limited) x 256 CUs
    disk_hist_kernel<<<768, 256, 0, stream>>>(pos, vel, mass, ghist, n);
    disk_finalize_kernel<<<1, 64, 0, stream>>>(ghist, out);
}